// Round 1
// baseline (71.224 us; speedup 1.0000x reference)
//
#include <hip/hip_runtime.h>
#include <math.h>

#define NBLK 2048
#define NTHR 256

// Combine two online-softmax partials (m1,s1) <- (m1,s1) ⊕ (m2,s2)
__device__ __forceinline__ void ms_combine(float& m, float& s, float m2, float s2) {
    float mn = fmaxf(m, m2);
    s = s * __expf(m - mn) + s2 * __expf(m2 - mn);
    m = mn;
}

// Pass 1: per-block online (max, sum exp) partials. One read of x.
__global__ __launch_bounds__(NTHR) void softmax_partials(
        const float* __restrict__ x, long n4, float* __restrict__ ws) {
    const float4* __restrict__ x4 = (const float4*)x;
    long tid    = (long)blockIdx.x * blockDim.x + threadIdx.x;
    long stride = (long)gridDim.x * blockDim.x;

    float m = -INFINITY, s = 0.0f;
    for (long i = tid; i < n4; i += stride) {
        float4 v = x4[i];
        float vm = fmaxf(fmaxf(v.x, v.y), fmaxf(v.z, v.w));
        if (vm > m) { s *= __expf(m - vm); m = vm; }   // first iter: exp(-inf)=0, s stays 0
        s += __expf(v.x - m) + __expf(v.y - m)
           + __expf(v.z - m) + __expf(v.w - m);
    }

    // wave-64 butterfly-style reduce (shfl_down)
    #pragma unroll
    for (int off = 32; off > 0; off >>= 1) {
        float m2 = __shfl_down(m, off);
        float s2 = __shfl_down(s, off);
        ms_combine(m, s, m2, s2);
    }

    __shared__ float sm[NTHR / 64], ss[NTHR / 64];
    int wid = threadIdx.x >> 6;
    if ((threadIdx.x & 63) == 0) { sm[wid] = m; ss[wid] = s; }
    __syncthreads();
    if (threadIdx.x == 0) {
        m = sm[0]; s = ss[0];
        #pragma unroll
        for (int w = 1; w < NTHR / 64; ++w) ms_combine(m, s, sm[w], ss[w]);
        ws[blockIdx.x]             = m;
        ws[gridDim.x + blockIdx.x] = s;
    }
}

// Pass 2: single block combines NBLK partials -> ws[2*NBLK] = m_global,
// ws[2*NBLK+1] = 1/S. Tiny.
__global__ __launch_bounds__(NTHR) void softmax_finalize(float* __restrict__ ws, int nparts) {
    float m = -INFINITY, s = 0.0f;
    for (int i = threadIdx.x; i < nparts; i += blockDim.x) {
        ms_combine(m, s, ws[i], ws[nparts + i]);
    }
    #pragma unroll
    for (int off = 32; off > 0; off >>= 1) {
        float m2 = __shfl_down(m, off);
        float s2 = __shfl_down(s, off);
        ms_combine(m, s, m2, s2);
    }
    __shared__ float sm[NTHR / 64], ss[NTHR / 64];
    int wid = threadIdx.x >> 6;
    if ((threadIdx.x & 63) == 0) { sm[wid] = m; ss[wid] = s; }
    __syncthreads();
    if (threadIdx.x == 0) {
        m = sm[0]; s = ss[0];
        #pragma unroll
        for (int w = 1; w < NTHR / 64; ++w) ms_combine(m, s, sm[w], ss[w]);
        ws[2 * nparts]     = m;
        ws[2 * nparts + 1] = 1.0f / s;
    }
}

// Pass 3: out = exp(x - m) / S. One read of x (L3-warm), one write.
__global__ __launch_bounds__(NTHR) void softmax_write(
        const float* __restrict__ x, float* __restrict__ out, long n4,
        const float* __restrict__ scal) {
    const float gm   = scal[0];
    const float ginv = scal[1];
    const float4* __restrict__ x4 = (const float4*)x;
    float4* __restrict__ o4 = (float4*)out;
    long tid    = (long)blockIdx.x * blockDim.x + threadIdx.x;
    long stride = (long)gridDim.x * blockDim.x;
    for (long i = tid; i < n4; i += stride) {
        float4 v = x4[i];
        float4 o;
        o.x = __expf(v.x - gm) * ginv;
        o.y = __expf(v.y - gm) * ginv;
        o.z = __expf(v.z - gm) * ginv;
        o.w = __expf(v.w - gm) * ginv;
        o4[i] = o;
    }
}

extern "C" void kernel_launch(void* const* d_in, const int* in_sizes, int n_in,
                              void* d_out, int out_size, void* d_ws, size_t ws_size,
                              hipStream_t stream) {
    const float* x = (const float*)d_in[0];
    float* out     = (float*)d_out;
    float* ws      = (float*)d_ws;
    long n  = (long)in_sizes[0];
    long n4 = n >> 2;   // N = 2^25, divisible by 4

    softmax_partials<<<NBLK, NTHR, 0, stream>>>(x, n4, ws);
    softmax_finalize<<<1, NTHR, 0, stream>>>(ws, NBLK);
    softmax_write<<<NBLK, NTHR, 0, stream>>>(x, out, n4, ws + 2 * NBLK);
}

// Round 3
// 70.192 us; speedup vs baseline: 1.0147x; 1.0147x over previous
//
#include <hip/hip_runtime.h>
#include <math.h>

#define NBLK 2048
#define NTHR 256

typedef float f32x4 __attribute__((ext_vector_type(4)));

// Combine two online-softmax partials (m1,s1) <- (m1,s1) ⊕ (m2,s2)
__device__ __forceinline__ void ms_combine(float& m, float& s, float m2, float s2) {
    float mn = fmaxf(m, m2);
    s = s * __expf(m - mn) + s2 * __expf(m2 - mn);
    m = mn;
}

// Pass 1: per-block online (max, sum exp) partials. One read of x (allocates
// x into L2/L3 for pass 2's re-read).
__global__ __launch_bounds__(NTHR) void softmax_partials(
        const float* __restrict__ x, long n4, float* __restrict__ ws) {
    const f32x4* __restrict__ x4 = (const f32x4*)x;
    long tid    = (long)blockIdx.x * blockDim.x + threadIdx.x;
    long stride = (long)gridDim.x * blockDim.x;

    float m = -INFINITY, s = 0.0f;
    for (long i = tid; i < n4; i += stride) {
        f32x4 v = x4[i];
        float vm = fmaxf(fmaxf(v.x, v.y), fmaxf(v.z, v.w));
        if (vm > m) { s *= __expf(m - vm); m = vm; }   // first iter: exp(-inf)=0, s stays 0
        s += __expf(v.x - m) + __expf(v.y - m)
           + __expf(v.z - m) + __expf(v.w - m);
    }

    #pragma unroll
    for (int off = 32; off > 0; off >>= 1) {
        float m2 = __shfl_down(m, off);
        float s2 = __shfl_down(s, off);
        ms_combine(m, s, m2, s2);
    }

    __shared__ float sm[NTHR / 64], ss[NTHR / 64];
    int wid = threadIdx.x >> 6;
    if ((threadIdx.x & 63) == 0) { sm[wid] = m; ss[wid] = s; }
    __syncthreads();
    if (threadIdx.x == 0) {
        m = sm[0]; s = ss[0];
        #pragma unroll
        for (int w = 1; w < NTHR / 64; ++w) ms_combine(m, s, sm[w], ss[w]);
        ws[blockIdx.x]             = m;
        ws[gridDim.x + blockIdx.x] = s;
    }
}

// Pass 2: every block redundantly combines the NBLK partials (deterministic,
// identical result in all blocks), then writes out = exp(x - m) / S.
// x read should be L3-warm; output stores are non-temporal (evict-first) so
// they don't displace x from L2/L3.
__global__ __launch_bounds__(NTHR) void softmax_write(
        const float* __restrict__ x, float* __restrict__ out, long n4,
        const float* __restrict__ ws, int nparts) {
    // --- redundant global (m, 1/S) reduce: nparts/NTHR iters per thread ---
    float m = -INFINITY, s = 0.0f;
    for (int i = threadIdx.x; i < nparts; i += NTHR) {
        ms_combine(m, s, ws[i], ws[nparts + i]);
    }
    #pragma unroll
    for (int off = 32; off > 0; off >>= 1) {
        float m2 = __shfl_down(m, off);
        float s2 = __shfl_down(s, off);
        ms_combine(m, s, m2, s2);
    }
    __shared__ float sm[NTHR / 64], ss[NTHR / 64];
    __shared__ float g[2];
    int wid = threadIdx.x >> 6;
    if ((threadIdx.x & 63) == 0) { sm[wid] = m; ss[wid] = s; }
    __syncthreads();
    if (threadIdx.x == 0) {
        m = sm[0]; s = ss[0];
        #pragma unroll
        for (int w = 1; w < NTHR / 64; ++w) ms_combine(m, s, sm[w], ss[w]);
        g[0] = m;
        g[1] = 1.0f / s;
    }
    __syncthreads();
    const float gm   = g[0];
    const float ginv = g[1];

    // --- streaming write pass ---
    const f32x4* __restrict__ x4 = (const f32x4*)x;
    f32x4* __restrict__ o4 = (f32x4*)out;
    long tid    = (long)blockIdx.x * blockDim.x + threadIdx.x;
    long stride = (long)gridDim.x * blockDim.x;
    for (long i = tid; i < n4; i += stride) {
        f32x4 v = x4[i];
        f32x4 o;
        o.x = __expf(v.x - gm) * ginv;
        o.y = __expf(v.y - gm) * ginv;
        o.z = __expf(v.z - gm) * ginv;
        o.w = __expf(v.w - gm) * ginv;
        __builtin_nontemporal_store(o, &o4[i]);
    }
}

extern "C" void kernel_launch(void* const* d_in, const int* in_sizes, int n_in,
                              void* d_out, int out_size, void* d_ws, size_t ws_size,
                              hipStream_t stream) {
    const float* x = (const float*)d_in[0];
    float* out     = (float*)d_out;
    float* ws      = (float*)d_ws;
    long n  = (long)in_sizes[0];
    long n4 = n >> 2;   // N = 2^25, divisible by 4

    softmax_partials<<<NBLK, NTHR, 0, stream>>>(x, n4, ws);
    softmax_write<<<NBLK, NTHR, 0, stream>>>(x, out, n4, ws, NBLK);
}